// Round 3
// baseline (262.627 us; speedup 1.0000x reference)
//
#include <hip/hip_runtime.h>
#include <hip/hip_bf16.h>

// Problem constants: B=2, S=128, D=512, H=8, Dh=64
// Evidence (R1/R2): inputs are float32, output is float32.
#define B_  2
#define S_  128
#define D_  512
#define H_  8
#define DH_ 64
#define IGNORE_VAL (-1.0e6f)

__device__ __forceinline__ float blo(unsigned int w) { return __uint_as_float(w << 16); }
__device__ __forceinline__ float bhi(unsigned int w) { return __uint_as_float(w & 0xffff0000u); }
__device__ __forceinline__ float bf2f(unsigned short u) { return __uint_as_float(((unsigned int)u) << 16); }
__device__ __forceinline__ unsigned short f2bf(float f) {
    unsigned int x = __float_as_uint(f);
    return (unsigned short)((x + 0x7fffu + ((x >> 16) & 1u)) >> 16);
}

// ---------------- Kernel 1: fused projection GEMM ---------------------------
// A = x (256 x 512), virtual W = [W_kkq | Wv_a | Wv_b] (512 x 2560).
// Tile 64x64, BK=32, 256 threads (16x16), 4x4 outputs/thread.
// Col-block cb: 0..7 k1 | 8..15 k2 | 16..23 q | 24..31 va | 32..39 vb
// (each 64-col block lies entirely in one part; head n = cb&7 is uniform).
// Outputs head-major f32: arr[((b*H+n)*S + s)*64 + h]
#define PAD 68
__global__ __launch_bounds__(256) void proj_kernel(
    const float* __restrict__ x,
    const float* __restrict__ W_kkq, const float* __restrict__ b_kkq,
    const float* __restrict__ Wv_a,  const float* __restrict__ Wv_b,
    float* __restrict__ k1_ws, float* __restrict__ k2_ws, float* __restrict__ q_ws,
    float* __restrict__ va_ws, float* __restrict__ vb_ws)
{
    __shared__ __align__(16) float As[32][PAD];
    __shared__ __align__(16) float Ws[32][PAD];

    const int cb = blockIdx.x;           // 0..39
    const int rb = blockIdx.y;           // 0..3
    const int tid = threadIdx.x;
    const int tx = tid & 15, ty = tid >> 4;

    const int part = cb >> 3;            // 0 k1, 1 k2, 2 q, 3 va, 4 vb
    const float* Wbase; int wstride; int wcoloff;
    if (part <= 2) { Wbase = W_kkq; wstride = 1536; wcoloff = cb * 64; }
    else if (part == 3) { Wbase = Wv_a; wstride = 512; wcoloff = (cb - 24) * 64; }
    else { Wbase = Wv_b; wstride = 512; wcoloff = (cb - 32) * 64; }
    float* Obase = (part == 0) ? k1_ws : (part == 1) ? k2_ws : (part == 2) ? q_ws
                 : (part == 3) ? va_ws : vb_ws;

    float acc[4][4];
#pragma unroll
    for (int i = 0; i < 4; ++i)
#pragma unroll
        for (int j = 0; j < 4; ++j) acc[i][j] = 0.f;

    for (int k0 = 0; k0 < D_; k0 += 32) {
        // stage A: rows rb*64 .. +63, k k0..k0+31.  thread: kk=(tid&7)*4, m=tid>>3 (+32)
        {
            const int kk = (tid & 7) * 4, m0 = tid >> 3;
#pragma unroll
            for (int p = 0; p < 2; ++p) {
                int m = m0 + p * 32;
                float4 v = *reinterpret_cast<const float4*>(x + (size_t)(rb * 64 + m) * D_ + k0 + kk);
                As[kk + 0][m] = v.x; As[kk + 1][m] = v.y;
                As[kk + 2][m] = v.z; As[kk + 3][m] = v.w;
            }
        }
        // stage W: thread: n=(tid&15)*4, k=tid>>4 (+16)
        {
            const int n = (tid & 15) * 4, kq = tid >> 4;
#pragma unroll
            for (int p = 0; p < 2; ++p) {
                int k = kq + p * 16;
                float4 v = *reinterpret_cast<const float4*>(Wbase + (size_t)(k0 + k) * wstride + wcoloff + n);
                *reinterpret_cast<float4*>(&Ws[k][n]) = v;
            }
        }
        __syncthreads();
#pragma unroll
        for (int k = 0; k < 32; ++k) {
            float4 a4 = *reinterpret_cast<const float4*>(&As[k][ty * 4]);
            float4 w4 = *reinterpret_cast<const float4*>(&Ws[k][tx * 4]);
            float av[4] = {a4.x, a4.y, a4.z, a4.w};
            float wv[4] = {w4.x, w4.y, w4.z, w4.w};
#pragma unroll
            for (int i = 0; i < 4; ++i)
#pragma unroll
                for (int j = 0; j < 4; ++j) acc[i][j] += av[i] * wv[j];
        }
        __syncthreads();
    }

    // epilogue: bias (only kkq part) + head-major scatter
    const int n_head = cb & 7;
#pragma unroll
    for (int j = 0; j < 4; ++j) {
        const int h = tx * 4 + j;
        const float bias = (part <= 2) ? b_kkq[cb * 64 + h] : 0.f;
#pragma unroll
        for (int i = 0; i < 4; ++i) {
            const int row = rb * 64 + ty * 4 + i;      // b*128 + s
            const int b = row >> 7, s = row & 127;
            Obase[(((b * H_ + n_head) * S_ + s) << 6) + h] = acc[i][j] + bias;
        }
    }
}

// ---------------- Kernel 2: tri-way scores + joint softmax + marginals + z --
// grid (S, H, B), block 256. thread = (s = tid>>1, tg = tid&1) owns t in [tg*64, tg*64+64)
#define K_STRIDE 72      // ushorts per row (64 + 8 pad), 144 B: 16B-aligned rows
#define P_STRIDE 130     // ushorts per row for p matrix
__global__ __launch_bounds__(256) void tri_kernel(
    const float* __restrict__ k1_ws, const float* __restrict__ k2_ws,
    const float* __restrict__ q_ws,
    const float* __restrict__ va_ws, const float* __restrict__ vb_ws,
    const float* __restrict__ b_v,
    float* __restrict__ z_ws)
{
    const int qidx = blockIdx.x;
    const int n = blockIdx.y;
    const int b = blockIdx.z;
    const int head = b * H_ + n;
    const float* k1h = k1_ws + (size_t)head * S_ * DH_;
    const float* k2h = k2_ws + (size_t)head * S_ * DH_;
    const float* qrow = q_ws + (size_t)head * S_ * DH_ + qidx * DH_;
    const float* va_h = va_ws + (size_t)head * S_ * DH_;
    const float* vb_h = vb_ws + (size_t)head * S_ * DH_;

    __shared__ __align__(16) unsigned short sbuf[2 * S_ * K_STRIDE];   // 36864 B
    __shared__ float qv[DH_];
    __shared__ float red[256];
    __shared__ float As2[256];
    __shared__ float Asm[S_], Atm[S_];

    const int tid = threadIdx.x;
    if (tid < DH_) qv[tid] = qrow[tid];
    for (int i = tid; i < S_ * DH_; i += 256) {
        int r = i >> 6, h = i & 63;
        sbuf[r * K_STRIDE + h] = f2bf(k1h[i]);
        sbuf[S_ * K_STRIDE + r * K_STRIDE + h] = f2bf(k2h[i]);
    }
    __syncthreads();

    const int s = tid >> 1, tg = tid & 1;

    // a_s[h] = k1[s,h] * q[q,h]
    float a_s[64];
    {
        const uint4* r1 = reinterpret_cast<const uint4*>(sbuf + s * K_STRIDE);
#pragma unroll
        for (int i = 0; i < 8; ++i) {
            uint4 v = r1[i];
            int h = i * 8;
            a_s[h + 0] = blo(v.x) * qv[h + 0]; a_s[h + 1] = bhi(v.x) * qv[h + 1];
            a_s[h + 2] = blo(v.y) * qv[h + 2]; a_s[h + 3] = bhi(v.y) * qv[h + 3];
            a_s[h + 4] = blo(v.z) * qv[h + 4]; a_s[h + 5] = bhi(v.z) * qv[h + 5];
            a_s[h + 6] = blo(v.w) * qv[h + 6]; a_s[h + 7] = bhi(v.w) * qv[h + 7];
        }
    }

    // scores[s][t] for t = tg*64 + j
    float sc[64];
#pragma unroll
    for (int j = 0; j < 64; ++j) {
        const uint4* kr = reinterpret_cast<const uint4*>(sbuf + S_ * K_STRIDE + (tg * 64 + j) * K_STRIDE);
        float acc = 0.f;
#pragma unroll
        for (int i = 0; i < 8; ++i) {
            uint4 v = kr[i];
            int h = i * 8;
            acc += a_s[h + 0] * blo(v.x) + a_s[h + 1] * bhi(v.x)
                 + a_s[h + 2] * blo(v.y) + a_s[h + 3] * bhi(v.y)
                 + a_s[h + 4] * blo(v.z) + a_s[h + 5] * bhi(v.z)
                 + a_s[h + 6] * blo(v.w) + a_s[h + 7] * bhi(v.w);
        }
        sc[j] = acc;
    }

    // mask (t > q -> IGNORE) then scale by 1/Dh (reference order), local max
    float m = -3.4e38f;
#pragma unroll
    for (int j = 0; j < 64; ++j) {
        int t = tg * 64 + j;
        float v = (t > qidx) ? IGNORE_VAL : sc[j];
        v *= (1.f / 64.f);
        sc[j] = v;
        m = fmaxf(m, v);
    }

    // block max
    red[tid] = m;
    __syncthreads();
    for (int off = 128; off > 0; off >>= 1) {
        if (tid < off) red[tid] = fmaxf(red[tid], red[tid + off]);
        __syncthreads();
    }
    const float M = red[0];
    __syncthreads();

    // exp; store p (bf16) into sbuf (k1/k2 dead); row sums
    float ls = 0.f;
#pragma unroll
    for (int j = 0; j < 64; ++j) {
        float p = __expf(sc[j] - M);
        ls += p;
        sbuf[s * P_STRIDE + tg * 64 + j] = f2bf(p);
    }
    As2[s * 2 + tg] = ls;

    // total Z
    red[tid] = ls;
    __syncthreads();
    for (int off = 128; off > 0; off >>= 1) {
        if (tid < off) red[tid] += red[tid + off];
        __syncthreads();
    }
    const float Zv = red[0];
    __syncthreads();

    // marginals
    if (tid < S_) {
        Asm[tid] = As2[2 * tid] + As2[2 * tid + 1];
        float a = 0.f;
        for (int s2 = 0; s2 < S_; ++s2) a += bf2f(sbuf[s2 * P_STRIDE + tid]);
        Atm[tid] = a;
    }
    __syncthreads();

    // z[h] = (Sum_s As[s]*va[s,h] + Sum_t At[t]*vb[t,h]) / Z + b_v
    {
        const int h = tid & 63, w = tid >> 6;                 // w in 0..3
        const float* vsrc = (w < 2) ? va_h : vb_h;
        const float* wt = (w < 2) ? Asm : Atm;
        const int base = (w & 1) * 64;
        float acc = 0.f;
        for (int i = 0; i < 64; ++i)
            acc += wt[base + i] * vsrc[(size_t)(base + i) * DH_ + h];
        red[tid] = acc;
    }
    __syncthreads();
    if (tid < DH_) {
        float zv = red[tid] + red[64 + tid] + red[128 + tid] + red[192 + tid];
        zv = zv / Zv + b_v[n * DH_ + tid];
        z_ws[((size_t)(b * S_ + qidx) * (H_ * DH_)) + n * DH_ + tid] = zv;
    }
}

// ---------------- Kernel 3: out = z @ W_out + b_out (tiled GEMM, f32 out) ---
__global__ __launch_bounds__(256) void out_kernel(
    const float* __restrict__ z_ws,
    const float* __restrict__ W_out, const float* __restrict__ b_out,
    float* __restrict__ out)
{
    __shared__ __align__(16) float As[32][PAD];
    __shared__ __align__(16) float Ws[32][PAD];

    const int cb = blockIdx.x;           // 0..7
    const int rb = blockIdx.y;           // 0..3
    const int tid = threadIdx.x;
    const int tx = tid & 15, ty = tid >> 4;

    float acc[4][4];
#pragma unroll
    for (int i = 0; i < 4; ++i)
#pragma unroll
        for (int j = 0; j < 4; ++j) acc[i][j] = 0.f;

    for (int k0 = 0; k0 < 512; k0 += 32) {
        {
            const int kk = (tid & 7) * 4, m0 = tid >> 3;
#pragma unroll
            for (int p = 0; p < 2; ++p) {
                int m = m0 + p * 32;
                float4 v = *reinterpret_cast<const float4*>(z_ws + (size_t)(rb * 64 + m) * 512 + k0 + kk);
                As[kk + 0][m] = v.x; As[kk + 1][m] = v.y;
                As[kk + 2][m] = v.z; As[kk + 3][m] = v.w;
            }
        }
        {
            const int n = (tid & 15) * 4, kq = tid >> 4;
#pragma unroll
            for (int p = 0; p < 2; ++p) {
                int k = kq + p * 16;
                float4 v = *reinterpret_cast<const float4*>(W_out + (size_t)(k0 + k) * 512 + cb * 64 + n);
                *reinterpret_cast<float4*>(&Ws[k][n]) = v;
            }
        }
        __syncthreads();
#pragma unroll
        for (int k = 0; k < 32; ++k) {
            float4 a4 = *reinterpret_cast<const float4*>(&As[k][ty * 4]);
            float4 w4 = *reinterpret_cast<const float4*>(&Ws[k][tx * 4]);
            float av[4] = {a4.x, a4.y, a4.z, a4.w};
            float wv[4] = {w4.x, w4.y, w4.z, w4.w};
#pragma unroll
            for (int i = 0; i < 4; ++i)
#pragma unroll
                for (int j = 0; j < 4; ++j) acc[i][j] += av[i] * wv[j];
        }
        __syncthreads();
    }

#pragma unroll
    for (int j = 0; j < 4; ++j) {
        const int c = cb * 64 + tx * 4 + j;
        const float bias = b_out[c];
#pragma unroll
        for (int i = 0; i < 4; ++i) {
            const int row = rb * 64 + ty * 4 + i;
            out[(size_t)row * 512 + c] = acc[i][j] + bias;
        }
    }
}

// ---------------------------------------------------------------------------
extern "C" void kernel_launch(void* const* d_in, const int* in_sizes, int n_in,
                              void* d_out, int out_size, void* d_ws, size_t ws_size,
                              hipStream_t stream) {
    const float* x     = (const float*)d_in[0];
    const float* W_kkq = (const float*)d_in[1];
    const float* b_kkq = (const float*)d_in[2];
    const float* Wv_a  = (const float*)d_in[3];
    const float* Wv_b  = (const float*)d_in[4];
    const float* b_v   = (const float*)d_in[5];
    const float* W_out = (const float*)d_in[6];
    const float* b_out = (const float*)d_in[7];
    float* out = (float*)d_out;

    const size_t HE = (size_t)B_ * H_ * S_ * DH_;   // 131072
    float* ws = (float*)d_ws;
    float* k1_ws = ws;
    float* k2_ws = ws + HE;
    float* q_ws  = ws + 2 * HE;
    float* va_ws = ws + 3 * HE;
    float* vb_ws = ws + 4 * HE;
    float* z_ws  = ws + 5 * HE;

    proj_kernel<<<dim3(40, 4), 256, 0, stream>>>(x, W_kkq, b_kkq, Wv_a, Wv_b,
                                                 k1_ws, k2_ws, q_ws, va_ws, vb_ws);
    tri_kernel<<<dim3(S_, H_, B_), 256, 0, stream>>>(k1_ws, k2_ws, q_ws,
                                                     va_ws, vb_ws, b_v, z_ws);
    out_kernel<<<dim3(8, 4), 256, 0, stream>>>(z_ws, W_out, b_out, out);
}

// Round 4
// 145.756 us; speedup vs baseline: 1.8018x; 1.8018x over previous
//
#include <hip/hip_runtime.h>
#include <hip/hip_bf16.h>

// Problem constants: B=2, S=128, D=512, H=8, Dh=64. All I/O float32 (R2/R3 evidence).
#define B_  2
#define S_  128
#define D_  512
#define H_  8
#define DH_ 64
#define IGNORE_VAL (-1.0e6f)

typedef __attribute__((ext_vector_type(8))) short bf16x8;   // MFMA A/B frag (4 VGPRs)
typedef __attribute__((ext_vector_type(4))) float f32x4;    // MFMA C/D frag

__device__ __forceinline__ unsigned short f2bf(float f) {
    unsigned int x = __float_as_uint(f);
    return (unsigned short)((x + 0x7fffu + ((x >> 16) & 1u)) >> 16);
}

// ---------------- Kernel 1: fused projection GEMM ---------------------------
// A = x (256 x 512), virtual W = [W_kkq | Wv_a | Wv_b] (512 x 2560).
// Tile 32x64, BK=32, grid (40, 8) = 320 blocks for occupancy.
// cb: 0..7 k1 | 8..15 k2 | 16..23 q | 24..31 va | 32..39 vb (head n = cb&7).
// Outputs head-major f32: arr[((b*H+n)*S + s)*64 + h]
__global__ __launch_bounds__(256) void proj_kernel(
    const float* __restrict__ x,
    const float* __restrict__ W_kkq, const float* __restrict__ b_kkq,
    const float* __restrict__ Wv_a,  const float* __restrict__ Wv_b,
    float* __restrict__ k1_ws, float* __restrict__ k2_ws, float* __restrict__ q_ws,
    float* __restrict__ va_ws, float* __restrict__ vb_ws)
{
    __shared__ __align__(16) float As[32][36];
    __shared__ __align__(16) float Ws[32][68];

    const int cb = blockIdx.x;           // 0..39
    const int rb = blockIdx.y;           // 0..7 (32 rows each)
    const int tid = threadIdx.x;
    const int tx = tid & 15, ty = tid >> 4;

    const int part = cb >> 3;            // 0 k1, 1 k2, 2 q, 3 va, 4 vb
    const float* Wbase; int wstride; int wcoloff;
    if (part <= 2) { Wbase = W_kkq; wstride = 1536; wcoloff = cb * 64; }
    else if (part == 3) { Wbase = Wv_a; wstride = 512; wcoloff = (cb - 24) * 64; }
    else { Wbase = Wv_b; wstride = 512; wcoloff = (cb - 32) * 64; }
    float* Obase = (part == 0) ? k1_ws : (part == 1) ? k2_ws : (part == 2) ? q_ws
                 : (part == 3) ? va_ws : vb_ws;

    float acc[2][4];
#pragma unroll
    for (int i = 0; i < 2; ++i)
#pragma unroll
        for (int j = 0; j < 4; ++j) acc[i][j] = 0.f;

    for (int k0 = 0; k0 < D_; k0 += 32) {
        {   // stage A: 32 rows x 32 k (1 float4/thread)
            const int kk = (tid & 7) * 4, m = tid >> 3;
            float4 v = *reinterpret_cast<const float4*>(x + (size_t)(rb * 32 + m) * D_ + k0 + kk);
            As[kk + 0][m] = v.x; As[kk + 1][m] = v.y;
            As[kk + 2][m] = v.z; As[kk + 3][m] = v.w;
        }
        {   // stage W: 32 k x 64 n (2 float4/thread)
            const int nn = (tid & 15) * 4, kq = tid >> 4;
#pragma unroll
            for (int p = 0; p < 2; ++p) {
                int k = kq + p * 16;
                float4 v = *reinterpret_cast<const float4*>(Wbase + (size_t)(k0 + k) * wstride + wcoloff + nn);
                *reinterpret_cast<float4*>(&Ws[k][nn]) = v;
            }
        }
        __syncthreads();
#pragma unroll
        for (int k = 0; k < 32; ++k) {
            float a0 = As[k][ty * 2], a1 = As[k][ty * 2 + 1];
            float4 w4 = *reinterpret_cast<const float4*>(&Ws[k][tx * 4]);
            acc[0][0] += a0 * w4.x; acc[0][1] += a0 * w4.y;
            acc[0][2] += a0 * w4.z; acc[0][3] += a0 * w4.w;
            acc[1][0] += a1 * w4.x; acc[1][1] += a1 * w4.y;
            acc[1][2] += a1 * w4.z; acc[1][3] += a1 * w4.w;
        }
        __syncthreads();
    }

    const int n_head = cb & 7;
#pragma unroll
    for (int j = 0; j < 4; ++j) {
        const int h = tx * 4 + j;
        const float bias = (part <= 2) ? b_kkq[cb * 64 + h] : 0.f;
#pragma unroll
        for (int i = 0; i < 2; ++i) {
            const int row = rb * 32 + ty * 2 + i;      // b*128 + s
            const int b = row >> 7, s = row & 127;
            Obase[(((b * H_ + n_head) * S_ + s) << 6) + h] = acc[i][j] + bias;
        }
    }
}

// ---------------- Kernel 2: MFMA tri-scores + softmax marginals + z ---------
// Block = (q, n, b), 256 thr = 4 waves. Wave w owns score rows s in [32w, 32w+32).
// scores = (k1 .* q) @ k2^T via mfma_f32_16x16x32_bf16, 128x128x64.
// P never materialized: only row sums (As), col sums (At), total Z, max M.
#define K2S 72   // ushort stride for k2 LDS rows
__global__ __launch_bounds__(256) void tri_kernel(
    const float* __restrict__ k1_ws, const float* __restrict__ k2_ws,
    const float* __restrict__ q_ws,
    const float* __restrict__ va_ws, const float* __restrict__ vb_ws,
    const float* __restrict__ b_v,
    float* __restrict__ z_ws)
{
    const int qidx = blockIdx.x;
    const int n = blockIdx.y;
    const int b = blockIdx.z;
    const int head = b * H_ + n;
    const float* k1h = k1_ws + (size_t)head * S_ * DH_;
    const float* k2h = k2_ws + (size_t)head * S_ * DH_;
    const float* qrow = q_ws + (size_t)head * S_ * DH_ + qidx * DH_;
    const float* va_h = va_ws + (size_t)head * S_ * DH_;
    const float* vb_h = vb_ws + (size_t)head * S_ * DH_;

    __shared__ __align__(16) unsigned short k2s[S_ * K2S];   // 18432 B
    __shared__ __align__(16) float qv[DH_];
    __shared__ float Asm[S_], Atm[S_];
    __shared__ float Atp[4][S_];
    __shared__ float redm[4], reds[4];
    __shared__ float red[256];

    const int tid = threadIdx.x;
    const int lane = tid & 63, wv = tid >> 6;
    const int row16 = lane & 15, quad = lane >> 4;

    if (tid < DH_) qv[tid] = qrow[tid];
    for (int i = tid; i < S_ * DH_; i += 256)
        k2s[(i >> 6) * K2S + (i & 63)] = f2bf(k2h[i]);
    __syncthreads();

    // A fragments from global: A'[s][h] = k1[s][h] * q[h] -> bf16
    // A-layout (16x16x32): lane holds A[m = lane&15][k = quad*8 + j]
    bf16x8 afrag[2][2];
#pragma unroll
    for (int mt = 0; mt < 2; ++mt) {
        const int srow = (wv * 2 + mt) * 16 + row16;
#pragma unroll
        for (int kk = 0; kk < 2; ++kk) {
            const int k = kk * 32 + quad * 8;
            const float4 u0 = *reinterpret_cast<const float4*>(k1h + (size_t)srow * DH_ + k);
            const float4 u1 = *reinterpret_cast<const float4*>(k1h + (size_t)srow * DH_ + k + 4);
            const float4 q0 = *reinterpret_cast<const float4*>(&qv[k]);
            const float4 q1 = *reinterpret_cast<const float4*>(&qv[k + 4]);
            bf16x8 f;
            f[0] = (short)f2bf(u0.x * q0.x); f[1] = (short)f2bf(u0.y * q0.y);
            f[2] = (short)f2bf(u0.z * q0.z); f[3] = (short)f2bf(u0.w * q0.w);
            f[4] = (short)f2bf(u1.x * q1.x); f[5] = (short)f2bf(u1.y * q1.y);
            f[6] = (short)f2bf(u1.z * q1.z); f[7] = (short)f2bf(u1.w * q1.w);
            afrag[mt][kk] = f;
        }
    }

    // MFMA: acc[mt][nt], C-layout col = nt*16 + (lane&15), row = mt-tile row quad*4+r
    f32x4 acc[2][8];
#pragma unroll
    for (int mt = 0; mt < 2; ++mt)
#pragma unroll
        for (int nt = 0; nt < 8; ++nt) acc[mt][nt] = (f32x4){0.f, 0.f, 0.f, 0.f};

#pragma unroll
    for (int kk = 0; kk < 2; ++kk) {
#pragma unroll
        for (int nt = 0; nt < 8; ++nt) {
            bf16x8 bfrag = *reinterpret_cast<const bf16x8*>(
                &k2s[(nt * 16 + row16) * K2S + kk * 32 + quad * 8]);
            acc[0][nt] = __builtin_amdgcn_mfma_f32_16x16x32_bf16(afrag[0][kk], bfrag, acc[0][nt], 0, 0, 0);
            acc[1][nt] = __builtin_amdgcn_mfma_f32_16x16x32_bf16(afrag[1][kk], bfrag, acc[1][nt], 0, 0, 0);
        }
    }

    // mask (t > q -> IGNORE) then scale 1/Dh (reference order); local max
    float mloc = -3.4e38f;
#pragma unroll
    for (int nt = 0; nt < 8; ++nt) {
        const int t = nt * 16 + row16;
        const bool msk = (t > qidx);
#pragma unroll
        for (int mt = 0; mt < 2; ++mt)
#pragma unroll
            for (int r = 0; r < 4; ++r) {
                float v = msk ? IGNORE_VAL : acc[mt][nt][r];
                v *= (1.f / 64.f);
                acc[mt][nt][r] = v;
                mloc = fmaxf(mloc, v);
            }
    }
#pragma unroll
    for (int m = 1; m < 64; m <<= 1) mloc = fmaxf(mloc, __shfl_xor(mloc, m, 64));
    if (lane == 0) redm[wv] = mloc;
    __syncthreads();
    const float M = fmaxf(fmaxf(redm[0], redm[1]), fmaxf(redm[2], redm[3]));

    // exp + in-register partial sums
    float rs[2][4], cs[8], tot = 0.f;
#pragma unroll
    for (int nt = 0; nt < 8; ++nt) cs[nt] = 0.f;
#pragma unroll
    for (int mt = 0; mt < 2; ++mt)
#pragma unroll
        for (int r = 0; r < 4; ++r) {
            float rr = 0.f;
#pragma unroll
            for (int nt = 0; nt < 8; ++nt) {
                float p = __expf(acc[mt][nt][r] - M);
                rr += p;
                cs[nt] += p;
            }
            rs[mt][r] = rr;
            tot += rr;
        }

    // row sums: reduce across lane bits 0..3 (col index); rows partition by (wv,mt,quad,r)
#pragma unroll
    for (int m = 1; m < 16; m <<= 1)
#pragma unroll
        for (int mt = 0; mt < 2; ++mt)
#pragma unroll
            for (int r = 0; r < 4; ++r) rs[mt][r] += __shfl_xor(rs[mt][r], m, 64);
    if (row16 == 0) {
#pragma unroll
        for (int mt = 0; mt < 2; ++mt)
#pragma unroll
            for (int r = 0; r < 4; ++r)
                Asm[(wv * 2 + mt) * 16 + quad * 4 + r] = rs[mt][r];
    }

    // col sums: reduce across lane bits 4..5 (row quad); then cross-wave partials
#pragma unroll
    for (int m = 16; m < 64; m <<= 1)
#pragma unroll
        for (int nt = 0; nt < 8; ++nt) cs[nt] += __shfl_xor(cs[nt], m, 64);
    if (quad == 0) {
#pragma unroll
        for (int nt = 0; nt < 8; ++nt) Atp[wv][nt * 16 + row16] = cs[nt];
    }

    // total Z
#pragma unroll
    for (int m = 1; m < 64; m <<= 1) tot += __shfl_xor(tot, m, 64);
    if (lane == 0) reds[wv] = tot;
    __syncthreads();

    const float Zv = reds[0] + reds[1] + reds[2] + reds[3];
    if (tid < S_) Atm[tid] = Atp[0][tid] + Atp[1][tid] + Atp[2][tid] + Atp[3][tid];
    __syncthreads();

    // z[h] = (Sum_s As[s]*va[s,h] + Sum_t At[t]*vb[t,h]) / Z + b_v
    {
        const int h = tid & 63, w = tid >> 6;
        const float* vsrc = (w < 2) ? va_h : vb_h;
        const float* wt = (w < 2) ? Asm : Atm;
        const int base = (w & 1) * 64;
        float a = 0.f;
        for (int i = 0; i < 64; ++i)
            a += wt[base + i] * vsrc[(size_t)(base + i) * DH_ + h];
        red[tid] = a;
    }
    __syncthreads();
    if (tid < DH_) {
        float zv = red[tid] + red[64 + tid] + red[128 + tid] + red[192 + tid];
        zv = zv / Zv + b_v[n * DH_ + tid];
        z_ws[((size_t)(b * S_ + qidx) * (H_ * DH_)) + n * DH_ + tid] = zv;
    }
}

// ---------------- Kernel 3: out = z @ W_out + b_out (32x32 tiles) -----------
__global__ __launch_bounds__(256) void out_kernel(
    const float* __restrict__ z_ws,
    const float* __restrict__ W_out, const float* __restrict__ b_out,
    float* __restrict__ out)
{
    __shared__ __align__(16) float As[32][36];
    __shared__ __align__(16) float Ws[32][36];

    const int cb = blockIdx.x;           // 0..15 (32 cols)
    const int rb = blockIdx.y;           // 0..7  (32 rows)
    const int tid = threadIdx.x;
    const int tx = tid & 15, ty = tid >> 4;

    float acc[2][2] = {{0.f, 0.f}, {0.f, 0.f}};

    for (int k0 = 0; k0 < 512; k0 += 32) {
        {
            const int kk = (tid & 7) * 4, m = tid >> 3;
            float4 v = *reinterpret_cast<const float4*>(z_ws + (size_t)(rb * 32 + m) * 512 + k0 + kk);
            As[kk + 0][m] = v.x; As[kk + 1][m] = v.y;
            As[kk + 2][m] = v.z; As[kk + 3][m] = v.w;
        }
        {
            const int nn = (tid & 7) * 4, k = tid >> 3;
            float4 v = *reinterpret_cast<const float4*>(W_out + (size_t)(k0 + k) * 512 + cb * 32 + nn);
            *reinterpret_cast<float4*>(&Ws[k][nn]) = v;
        }
        __syncthreads();
#pragma unroll
        for (int k = 0; k < 32; ++k) {
            float a0 = As[k][ty * 2], a1 = As[k][ty * 2 + 1];
            float w0 = Ws[k][tx * 2], w1 = Ws[k][tx * 2 + 1];
            acc[0][0] += a0 * w0; acc[0][1] += a0 * w1;
            acc[1][0] += a1 * w0; acc[1][1] += a1 * w1;
        }
        __syncthreads();
    }

#pragma unroll
    for (int j = 0; j < 2; ++j) {
        const int c = cb * 32 + tx * 2 + j;
        const float bias = b_out[c];
#pragma unroll
        for (int i = 0; i < 2; ++i) {
            const int row = rb * 32 + ty * 2 + i;
            out[(size_t)row * 512 + c] = acc[i][j] + bias;
        }
    }
}

// ---------------------------------------------------------------------------
extern "C" void kernel_launch(void* const* d_in, const int* in_sizes, int n_in,
                              void* d_out, int out_size, void* d_ws, size_t ws_size,
                              hipStream_t stream) {
    const float* x     = (const float*)d_in[0];
    const float* W_kkq = (const float*)d_in[1];
    const float* b_kkq = (const float*)d_in[2];
    const float* Wv_a  = (const float*)d_in[3];
    const float* Wv_b  = (const float*)d_in[4];
    const float* b_v   = (const float*)d_in[5];
    const float* W_out = (const float*)d_in[6];
    const float* b_out = (const float*)d_in[7];
    float* out = (float*)d_out;

    const size_t HE = (size_t)B_ * H_ * S_ * DH_;   // 131072
    float* ws = (float*)d_ws;
    float* k1_ws = ws;
    float* k2_ws = ws + HE;
    float* q_ws  = ws + 2 * HE;
    float* va_ws = ws + 3 * HE;
    float* vb_ws = ws + 4 * HE;
    float* z_ws  = ws + 5 * HE;

    proj_kernel<<<dim3(40, 8), 256, 0, stream>>>(x, W_kkq, b_kkq, Wv_a, Wv_b,
                                                 k1_ws, k2_ws, q_ws, va_ws, vb_ws);
    tri_kernel<<<dim3(S_, H_, B_), 256, 0, stream>>>(k1_ws, k2_ws, q_ws,
                                                     va_ws, vb_ws, b_v, z_ws);
    out_kernel<<<dim3(16, 8), 256, 0, stream>>>(z_ws, W_out, b_out, out);
}

// Round 5
// 136.365 us; speedup vs baseline: 1.9259x; 1.0689x over previous
//
#include <hip/hip_runtime.h>
#include <hip/hip_bf16.h>

// Problem constants: B=2, S=128, D=512, H=8, Dh=64. All I/O float32 (R2/R3 evidence).
#define B_  2
#define S_  128
#define D_  512
#define H_  8
#define DH_ 64
#define IGNORE_VAL (-1.0e6f)
#define QB  4        // queries per tri block

typedef __attribute__((ext_vector_type(8))) short bf16x8;   // MFMA A/B frag (4 VGPRs)
typedef __attribute__((ext_vector_type(4))) float f32x4;    // MFMA C/D frag

__device__ __forceinline__ unsigned short f2bf(float f) {
    unsigned int x = __float_as_uint(f);
    return (unsigned short)((x + 0x7fffu + ((x >> 16) & 1u)) >> 16);
}

// ---------------- Kernel 1: fused projection GEMM ---------------------------
// A = x (256 x 512), virtual W = [W_kkq | Wv_a | Wv_b] (512 x 2560).
// Tile 32x64, BK=32, grid (40, 8) = 320 blocks.
// cb: 0..7 k1 | 8..15 k2 | 16..23 q | 24..31 va | 32..39 vb (head n = cb&7).
// k1/q/va/vb head-major f32; k2 head-major bf16 (ushort) — tri only needs bf16 k2.
__global__ __launch_bounds__(256) void proj_kernel(
    const float* __restrict__ x,
    const float* __restrict__ W_kkq, const float* __restrict__ b_kkq,
    const float* __restrict__ Wv_a,  const float* __restrict__ Wv_b,
    float* __restrict__ k1_ws, unsigned short* __restrict__ k2bf, float* __restrict__ q_ws,
    float* __restrict__ va_ws, float* __restrict__ vb_ws)
{
    __shared__ __align__(16) float As[32][36];
    __shared__ __align__(16) float Ws[32][68];

    const int cb = blockIdx.x;           // 0..39
    const int rb = blockIdx.y;           // 0..7 (32 rows each)
    const int tid = threadIdx.x;
    const int tx = tid & 15, ty = tid >> 4;

    const int part = cb >> 3;            // 0 k1, 1 k2, 2 q, 3 va, 4 vb
    const float* Wbase; int wstride; int wcoloff;
    if (part <= 2) { Wbase = W_kkq; wstride = 1536; wcoloff = cb * 64; }
    else if (part == 3) { Wbase = Wv_a; wstride = 512; wcoloff = (cb - 24) * 64; }
    else { Wbase = Wv_b; wstride = 512; wcoloff = (cb - 32) * 64; }

    float acc[2][4];
#pragma unroll
    for (int i = 0; i < 2; ++i)
#pragma unroll
        for (int j = 0; j < 4; ++j) acc[i][j] = 0.f;

    for (int k0 = 0; k0 < D_; k0 += 32) {
        {   // stage A: 32 rows x 32 k (1 float4/thread)
            const int kk = (tid & 7) * 4, m = tid >> 3;
            float4 v = *reinterpret_cast<const float4*>(x + (size_t)(rb * 32 + m) * D_ + k0 + kk);
            As[kk + 0][m] = v.x; As[kk + 1][m] = v.y;
            As[kk + 2][m] = v.z; As[kk + 3][m] = v.w;
        }
        {   // stage W: 32 k x 64 n (2 float4/thread)
            const int nn = (tid & 15) * 4, kq = tid >> 4;
#pragma unroll
            for (int p = 0; p < 2; ++p) {
                int k = kq + p * 16;
                float4 v = *reinterpret_cast<const float4*>(Wbase + (size_t)(k0 + k) * wstride + wcoloff + nn);
                *reinterpret_cast<float4*>(&Ws[k][nn]) = v;
            }
        }
        __syncthreads();
#pragma unroll
        for (int k = 0; k < 32; ++k) {
            float a0 = As[k][ty * 2], a1 = As[k][ty * 2 + 1];
            float4 w4 = *reinterpret_cast<const float4*>(&Ws[k][tx * 4]);
            acc[0][0] += a0 * w4.x; acc[0][1] += a0 * w4.y;
            acc[0][2] += a0 * w4.z; acc[0][3] += a0 * w4.w;
            acc[1][0] += a1 * w4.x; acc[1][1] += a1 * w4.y;
            acc[1][2] += a1 * w4.z; acc[1][3] += a1 * w4.w;
        }
        __syncthreads();
    }

    const int n_head = cb & 7;
    float* Obase = (part == 0) ? k1_ws : (part == 2) ? q_ws
                 : (part == 3) ? va_ws : vb_ws;
#pragma unroll
    for (int i = 0; i < 2; ++i) {
        const int row = rb * 32 + ty * 2 + i;      // b*128 + s
        const int b = row >> 7, s = row & 127;
        const size_t obase = (((size_t)(b * H_ + n_head) * S_ + s) << 6);
#pragma unroll
        for (int j = 0; j < 4; ++j) {
            const int h = tx * 4 + j;
            const float bias = (part <= 2) ? b_kkq[cb * 64 + h] : 0.f;
            const float val = acc[i][j] + bias;
            if (part == 1) k2bf[obase + h] = f2bf(val);
            else           Obase[obase + h] = val;
        }
    }
}

// ---------------- Kernel 2: MFMA tri-scores + softmax marginals + z ---------
// Block = (4 q's, n, b), 256 thr = 4 waves. grid (32, 8, 2) = 512 blocks.
// scores_q = (k1 .* q) @ k2^T via mfma_f32_16x16x32_bf16, 128x128x64 per q.
// No max-shift: |scores/64| <~ 2 (masked -> exp underflows to exactly 0).
// P never materialized: only row sums (Asm), col sums (Atm), total Z per q.
#define K2S 72   // ushort stride for k2 LDS rows (144 B: 16B-aligned, 2-way banks)
__global__ __launch_bounds__(256) void tri_kernel(
    const float* __restrict__ k1_ws, const unsigned short* __restrict__ k2bf,
    const float* __restrict__ q_ws,
    const float* __restrict__ va_ws, const float* __restrict__ vb_ws,
    const float* __restrict__ b_v,
    float* __restrict__ z_ws)
{
    const int qbase = blockIdx.x * QB;
    const int n = blockIdx.y;
    const int b = blockIdx.z;
    const int head = b * H_ + n;
    const float* k1h = k1_ws + (size_t)head * S_ * DH_;
    const unsigned short* k2hb = k2bf + (size_t)head * S_ * DH_;
    const float* qh = q_ws + (size_t)head * S_ * DH_;
    const float* va_h = va_ws + (size_t)head * S_ * DH_;
    const float* vb_h = vb_ws + (size_t)head * S_ * DH_;

    __shared__ __align__(16) unsigned short k2s[S_ * K2S];   // 18432 B
    __shared__ __align__(16) float qv[QB][DH_];              // 1 KB
    __shared__ float Asm[QB][S_];                            // 2 KB
    __shared__ float Atm[QB][S_];                            // 2 KB
    __shared__ float Atp[QB][4][S_];                         // 8 KB
    __shared__ float reds[QB][4];
    __shared__ float zred[4][QB][DH_];                       // 4 KB

    const int tid = threadIdx.x;
    const int lane = tid & 63, wv = tid >> 6;
    const int row16 = lane & 15, quad = lane >> 4;

    // stage q vectors (coalesced) and k2 (bf16, 16B chunks into padded rows)
    if (tid < QB * DH_) qv[tid >> 6][tid & 63] = qh[(size_t)(qbase + (tid >> 6)) * DH_ + (tid & 63)];
#pragma unroll
    for (int it = 0; it < 4; ++it) {
        const int i8 = (tid + it * 256) * 8;           // element index, 8 ushorts/chunk
        const int r = i8 >> 6, c = i8 & 63;
        uint4 v = *reinterpret_cast<const uint4*>(k2hb + i8);
        *reinterpret_cast<uint4*>(&k2s[r * K2S + c]) = v;
    }

    // k1 f32 fragments, kept across the q-loop.
    // A-layout (16x16x32): lane holds A[m = lane&15][k = quad*8 + j]
    float k1f[2][2][8];
#pragma unroll
    for (int mt = 0; mt < 2; ++mt) {
        const int srow = (wv * 2 + mt) * 16 + row16;
#pragma unroll
        for (int kk = 0; kk < 2; ++kk) {
            const int k = kk * 32 + quad * 8;
            const float4 u0 = *reinterpret_cast<const float4*>(k1h + (size_t)srow * DH_ + k);
            const float4 u1 = *reinterpret_cast<const float4*>(k1h + (size_t)srow * DH_ + k + 4);
            k1f[mt][kk][0] = u0.x; k1f[mt][kk][1] = u0.y; k1f[mt][kk][2] = u0.z; k1f[mt][kk][3] = u0.w;
            k1f[mt][kk][4] = u1.x; k1f[mt][kk][5] = u1.y; k1f[mt][kk][6] = u1.z; k1f[mt][kk][7] = u1.w;
        }
    }
    __syncthreads();

    for (int qq = 0; qq < QB; ++qq) {
        const int qidx = qbase + qq;

        // A' = k1 .* q  -> bf16 fragments
        bf16x8 afrag[2][2];
#pragma unroll
        for (int mt = 0; mt < 2; ++mt)
#pragma unroll
            for (int kk = 0; kk < 2; ++kk) {
                const int k = kk * 32 + quad * 8;
                bf16x8 f;
#pragma unroll
                for (int j = 0; j < 8; ++j)
                    f[j] = (short)f2bf(k1f[mt][kk][j] * qv[qq][k + j]);
                afrag[mt][kk] = f;
            }

        // MFMA: C-layout col = nt*16 + (lane&15), row = (wv*2+mt)*16 + quad*4 + r
        f32x4 acc[2][8];
#pragma unroll
        for (int mt = 0; mt < 2; ++mt)
#pragma unroll
            for (int nt = 0; nt < 8; ++nt) acc[mt][nt] = (f32x4){0.f, 0.f, 0.f, 0.f};
#pragma unroll
        for (int kk = 0; kk < 2; ++kk)
#pragma unroll
            for (int nt = 0; nt < 8; ++nt) {
                bf16x8 bfrag = *reinterpret_cast<const bf16x8*>(
                    &k2s[(nt * 16 + row16) * K2S + kk * 32 + quad * 8]);
                acc[0][nt] = __builtin_amdgcn_mfma_f32_16x16x32_bf16(afrag[0][kk], bfrag, acc[0][nt], 0, 0, 0);
                acc[1][nt] = __builtin_amdgcn_mfma_f32_16x16x32_bf16(afrag[1][kk], bfrag, acc[1][nt], 0, 0, 0);
            }

        // mask (t > q -> IGNORE) then scale 1/Dh; exp (no max-shift); partial sums
        float rs[2][4], cs[8], tot = 0.f;
#pragma unroll
        for (int nt = 0; nt < 8; ++nt) cs[nt] = 0.f;
#pragma unroll
        for (int mt = 0; mt < 2; ++mt)
#pragma unroll
            for (int r = 0; r < 4; ++r) rs[mt][r] = 0.f;
#pragma unroll
        for (int nt = 0; nt < 8; ++nt) {
            const int t = nt * 16 + row16;
            const bool msk = (t > qidx);
#pragma unroll
            for (int mt = 0; mt < 2; ++mt)
#pragma unroll
                for (int r = 0; r < 4; ++r) {
                    float v = msk ? IGNORE_VAL : acc[mt][nt][r];
                    float p = __expf(v * (1.f / 64.f));
                    rs[mt][r] += p;
                    cs[nt] += p;
                }
        }

        // row sums: reduce across lane bits 0..3 (col index)
#pragma unroll
        for (int m = 1; m < 16; m <<= 1)
#pragma unroll
            for (int mt = 0; mt < 2; ++mt)
#pragma unroll
                for (int r = 0; r < 4; ++r) rs[mt][r] += __shfl_xor(rs[mt][r], m, 64);
        if (row16 == 0) {
#pragma unroll
            for (int mt = 0; mt < 2; ++mt)
#pragma unroll
                for (int r = 0; r < 4; ++r)
                    Asm[qq][(wv * 2 + mt) * 16 + quad * 4 + r] = rs[mt][r];
        }

        // col sums: reduce across lane bits 4..5 (row quad) -> per-wave partials
#pragma unroll
        for (int m = 16; m < 64; m <<= 1)
#pragma unroll
            for (int nt = 0; nt < 8; ++nt) cs[nt] += __shfl_xor(cs[nt], m, 64);
        if (quad == 0) {
#pragma unroll
            for (int nt = 0; nt < 8; ++nt) Atp[qq][wv][nt * 16 + row16] = cs[nt];
        }

        // total Z partial (per wave)
        tot = rs[0][0] + rs[0][1] + rs[0][2] + rs[0][3]
            + rs[1][0] + rs[1][1] + rs[1][2] + rs[1][3];   // already col-reduced
#pragma unroll
        for (int m = 16; m < 64; m <<= 1) tot += __shfl_xor(tot, m, 64);
        if (lane == 0) reds[qq][wv] = tot;
    }
    __syncthreads();

    // combine At partials
    for (int i = tid; i < QB * S_; i += 256) {
        const int qq = i >> 7, t = i & 127;
        Atm[qq][t] = Atp[qq][0][t] + Atp[qq][1][t] + Atp[qq][2][t] + Atp[qq][3][t];
    }
    __syncthreads();

    // epilogue, s-major: read va/vb rows once, FMA into 4 q-accumulators
    {
        const int h = tid & 63, w = tid >> 6;
        float za[QB] = {0.f, 0.f, 0.f, 0.f};
        for (int i = 0; i < 32; ++i) {
            const int s = w * 32 + i;
            const float va_v = va_h[(size_t)s * DH_ + h];
            const float vb_v = vb_h[(size_t)s * DH_ + h];
#pragma unroll
            for (int qq = 0; qq < QB; ++qq)
                za[qq] += Asm[qq][s] * va_v + Atm[qq][s] * vb_v;
        }
#pragma unroll
        for (int qq = 0; qq < QB; ++qq) zred[w][qq][h] = za[qq];
    }
    __syncthreads();

    {
        const int qq = tid >> 6, h = tid & 63;
        const float Zv = reds[qq][0] + reds[qq][1] + reds[qq][2] + reds[qq][3];
        float zv = zred[0][qq][h] + zred[1][qq][h] + zred[2][qq][h] + zred[3][qq][h];
        zv = zv / Zv + b_v[n * DH_ + h];
        z_ws[((size_t)(b * S_ + qbase + qq) * (H_ * DH_)) + n * DH_ + h] = zv;
    }
}

// ---------------- Kernel 3: out = z @ W_out + b_out (32x32 tiles) -----------
__global__ __launch_bounds__(256) void out_kernel(
    const float* __restrict__ z_ws,
    const float* __restrict__ W_out, const float* __restrict__ b_out,
    float* __restrict__ out)
{
    __shared__ __align__(16) float As[32][36];
    __shared__ __align__(16) float Ws[32][36];

    const int cb = blockIdx.x;           // 0..15 (32 cols)
    const int rb = blockIdx.y;           // 0..7  (32 rows)
    const int tid = threadIdx.x;
    const int tx = tid & 15, ty = tid >> 4;

    float acc[2][2] = {{0.f, 0.f}, {0.f, 0.f}};

    for (int k0 = 0; k0 < 512; k0 += 32) {
        {
            const int kk = (tid & 7) * 4, m = tid >> 3;
            float4 v = *reinterpret_cast<const float4*>(z_ws + (size_t)(rb * 32 + m) * 512 + k0 + kk);
            As[kk + 0][m] = v.x; As[kk + 1][m] = v.y;
            As[kk + 2][m] = v.z; As[kk + 3][m] = v.w;
        }
        {
            const int nn = (tid & 7) * 4, k = tid >> 3;
            float4 v = *reinterpret_cast<const float4*>(W_out + (size_t)(k0 + k) * 512 + cb * 32 + nn);
            *reinterpret_cast<float4*>(&Ws[k][nn]) = v;
        }
        __syncthreads();
#pragma unroll
        for (int k = 0; k < 32; ++k) {
            float a0 = As[k][ty * 2], a1 = As[k][ty * 2 + 1];
            float w0 = Ws[k][tx * 2], w1 = Ws[k][tx * 2 + 1];
            acc[0][0] += a0 * w0; acc[0][1] += a0 * w1;
            acc[1][0] += a1 * w0; acc[1][1] += a1 * w1;
        }
        __syncthreads();
    }

#pragma unroll
    for (int j = 0; j < 2; ++j) {
        const int c = cb * 32 + tx * 2 + j;
        const float bias = b_out[c];
#pragma unroll
        for (int i = 0; i < 2; ++i) {
            const int row = rb * 32 + ty * 2 + i;
            out[(size_t)row * 512 + c] = acc[i][j] + bias;
        }
    }
}

// ---------------------------------------------------------------------------
extern "C" void kernel_launch(void* const* d_in, const int* in_sizes, int n_in,
                              void* d_out, int out_size, void* d_ws, size_t ws_size,
                              hipStream_t stream) {
    const float* x     = (const float*)d_in[0];
    const float* W_kkq = (const float*)d_in[1];
    const float* b_kkq = (const float*)d_in[2];
    const float* Wv_a  = (const float*)d_in[3];
    const float* Wv_b  = (const float*)d_in[4];
    const float* b_v   = (const float*)d_in[5];
    const float* W_out = (const float*)d_in[6];
    const float* b_out = (const float*)d_in[7];
    float* out = (float*)d_out;

    const size_t HE = (size_t)B_ * H_ * S_ * DH_;   // 131072
    float* ws = (float*)d_ws;
    float* k1_ws = ws;
    float* q_ws  = ws + HE;
    float* va_ws = ws + 2 * HE;
    float* vb_ws = ws + 3 * HE;
    float* z_ws  = ws + 4 * HE;                      // HE floats (B*S x 512)
    unsigned short* k2bf = (unsigned short*)(ws + 5 * HE);  // HE ushorts

    proj_kernel<<<dim3(40, 8), 256, 0, stream>>>(x, W_kkq, b_kkq, Wv_a, Wv_b,
                                                 k1_ws, k2bf, q_ws, va_ws, vb_ws);
    tri_kernel<<<dim3(S_ / QB, H_, B_), 256, 0, stream>>>(k1_ws, k2bf, q_ws,
                                                          va_ws, vb_ws, b_v, z_ws);
    out_kernel<<<dim3(16, 8), 256, 0, stream>>>(z_ws, W_out, b_out, out);
}

// Round 6
// 119.304 us; speedup vs baseline: 2.2013x; 1.1430x over previous
//
#include <hip/hip_runtime.h>
#include <hip/hip_bf16.h>

// Problem constants: B=2, S=128, D=512, H=8, Dh=64. All I/O float32 (R2/R3 evidence).
#define B_  2
#define S_  128
#define D_  512
#define H_  8
#define DH_ 64
#define IGNORE_VAL (-1.0e6f)
#define QB  4        // queries per tri block

#define XT_ST 72     // ushort stride for row-major A tiles (16B-aligned rows)
#define WT_ST 66     // ushort stride for k-major W tiles (2-way banks on strided u16 reads)

typedef __attribute__((ext_vector_type(8))) short bf16x8;   // MFMA A/B frag (4 VGPRs)
typedef __attribute__((ext_vector_type(4))) float f32x4;    // MFMA C/D frag

__device__ __forceinline__ unsigned short f2bf(float f) {
    unsigned int x = __float_as_uint(f);
    return (unsigned short)((x + 0x7fffu + ((x >> 16) & 1u)) >> 16);
}

// ---------------- Kernel 1: fused projection GEMM (bf16 MFMA) ---------------
// A = x (256 x 512), virtual W = [W_kkq | Wv_a | Wv_b] (512 x 2560).
// Tile 32 rows x 64 cols, BK=64, grid (40, 8) = 320 blocks, 4 waves.
// cb: 0..7 k1 | 8..15 k2 | 16..23 q | 24..31 va | 32..39 vb (head n = cb&7).
// k1/q/va/vb head-major f32; k2 head-major bf16.
__global__ __launch_bounds__(256) void proj_kernel(
    const float* __restrict__ x,
    const float* __restrict__ W_kkq, const float* __restrict__ b_kkq,
    const float* __restrict__ Wv_a,  const float* __restrict__ Wv_b,
    float* __restrict__ k1_ws, unsigned short* __restrict__ k2bf, float* __restrict__ q_ws,
    float* __restrict__ va_ws, float* __restrict__ vb_ws)
{
    __shared__ __align__(16) unsigned short xs[32 * XT_ST];   // 4608 B
    __shared__ __align__(16) unsigned short Wt[64 * WT_ST];   // 8448 B

    const int cb = blockIdx.x;           // 0..39
    const int rb = blockIdx.y;           // 0..7 (32 rows)
    const int tid = threadIdx.x;
    const int lane = tid & 63, wvx = tid >> 6;
    const int n16 = lane & 15, quad = lane >> 4;

    const int part = cb >> 3;            // 0 k1, 1 k2, 2 q, 3 va, 4 vb
    const float* Wbase; int wstride; int wcoloff;
    if (part <= 2) { Wbase = W_kkq; wstride = 1536; wcoloff = cb * 64; }
    else if (part == 3) { Wbase = Wv_a; wstride = 512; wcoloff = (cb - 24) * 64; }
    else { Wbase = Wv_b; wstride = 512; wcoloff = (cb - 32) * 64; }

    f32x4 acc[2];
    acc[0] = (f32x4){0.f, 0.f, 0.f, 0.f};
    acc[1] = (f32x4){0.f, 0.f, 0.f, 0.f};

    for (int k0 = 0; k0 < D_; k0 += 64) {
        {   // stage x tile: 32 rows x 64 k, f32 -> bf16, one uint4/thread
            const int m = tid >> 3, k8 = (tid & 7) * 8;
            const float* src = x + (size_t)(rb * 32 + m) * D_ + k0 + k8;
            const float4 a = *reinterpret_cast<const float4*>(src);
            const float4 b4 = *reinterpret_cast<const float4*>(src + 4);
            uint4 pk;
            pk.x = f2bf(a.x)  | ((unsigned)f2bf(a.y)  << 16);
            pk.y = f2bf(a.z)  | ((unsigned)f2bf(a.w)  << 16);
            pk.z = f2bf(b4.x) | ((unsigned)f2bf(b4.y) << 16);
            pk.w = f2bf(b4.z) | ((unsigned)f2bf(b4.w) << 16);
            *reinterpret_cast<uint4*>(&xs[m * XT_ST + k8]) = pk;
        }
        {   // stage W tile k-major: Wt[k][n], 64 k x 64 n, coalesced reads
#pragma unroll
            for (int p = 0; p < 4; ++p) {
                const int k = p * 16 + (tid >> 4);
                const int nb = (tid & 15) * 4;
                const float4 v = *reinterpret_cast<const float4*>(
                    Wbase + (size_t)(k0 + k) * wstride + wcoloff + nb);
                *reinterpret_cast<unsigned int*>(&Wt[k * WT_ST + nb]) =
                    f2bf(v.x) | ((unsigned)f2bf(v.y) << 16);
                *reinterpret_cast<unsigned int*>(&Wt[k * WT_ST + nb + 2]) =
                    f2bf(v.z) | ((unsigned)f2bf(v.w) << 16);
            }
        }
        __syncthreads();
#pragma unroll
        for (int kk = 0; kk < 2; ++kk) {
            // B-frag: lane holds B[n = lane&15][k = quad*8+j]; B[n][k] = W[k][n]
            bf16x8 bf;
#pragma unroll
            for (int j = 0; j < 8; ++j)
                bf[j] = (short)Wt[(kk * 32 + quad * 8 + j) * WT_ST + wvx * 16 + n16];
#pragma unroll
            for (int mt = 0; mt < 2; ++mt) {
                const bf16x8 af = *reinterpret_cast<const bf16x8*>(
                    &xs[(mt * 16 + n16) * XT_ST + kk * 32 + quad * 8]);
                acc[mt] = __builtin_amdgcn_mfma_f32_16x16x32_bf16(af, bf, acc[mt], 0, 0, 0);
            }
        }
        __syncthreads();
    }

    // epilogue: C row = mt*16 + quad*4 + r, col = wvx*16 + n16 (m89 layout)
    const int n_head = cb & 7;
    const int h = wvx * 16 + n16;
    const float bias = (part <= 2) ? b_kkq[cb * 64 + h] : 0.f;
    float* Obase = (part == 0) ? k1_ws : (part == 2) ? q_ws
                 : (part == 3) ? va_ws : vb_ws;
#pragma unroll
    for (int mt = 0; mt < 2; ++mt)
#pragma unroll
        for (int r = 0; r < 4; ++r) {
            const int row = rb * 32 + mt * 16 + quad * 4 + r;   // b*128 + s
            const int b = row >> 7, s = row & 127;
            const size_t o = (((size_t)(b * H_ + n_head) * S_ + s) << 6) + h;
            const float val = acc[mt][r] + bias;
            if (part == 1) k2bf[o] = f2bf(val);
            else           Obase[o] = val;
        }
}

// ---------------- Kernel 2: MFMA tri-scores + softmax marginals + z ---------
// Block = (4 q's, n, b), 256 thr = 4 waves. grid (32, 8, 2) = 512 blocks.
// scores_q = (k1 .* q) @ k2^T via mfma_f32_16x16x32_bf16, 128x128x64 per q.
// No max-shift: |scores/64| <~ 2 (masked -> exp underflows to exactly 0).
// P never materialized: only row sums (Asm), col sums (Atm), total Z per q.
#define K2S 72   // ushort stride for k2 LDS rows
__global__ __launch_bounds__(256) void tri_kernel(
    const float* __restrict__ k1_ws, const unsigned short* __restrict__ k2bf,
    const float* __restrict__ q_ws,
    const float* __restrict__ va_ws, const float* __restrict__ vb_ws,
    const float* __restrict__ b_v,
    unsigned short* __restrict__ z_bf)
{
    const int qbase = blockIdx.x * QB;
    const int n = blockIdx.y;
    const int b = blockIdx.z;
    const int head = b * H_ + n;
    const float* k1h = k1_ws + (size_t)head * S_ * DH_;
    const unsigned short* k2hb = k2bf + (size_t)head * S_ * DH_;
    const float* qh = q_ws + (size_t)head * S_ * DH_;
    const float* va_h = va_ws + (size_t)head * S_ * DH_;
    const float* vb_h = vb_ws + (size_t)head * S_ * DH_;

    __shared__ __align__(16) unsigned short k2s[S_ * K2S];   // 18432 B
    __shared__ __align__(16) float qv[QB][DH_];
    __shared__ float Asm[QB][S_];
    __shared__ float Atm[QB][S_];
    __shared__ float Atp[QB][4][S_];
    __shared__ float reds[QB][4];
    __shared__ float zred[4][QB][DH_];

    const int tid = threadIdx.x;
    const int lane = tid & 63, wv = tid >> 6;
    const int row16 = lane & 15, quad = lane >> 4;

    if (tid < QB * DH_) qv[tid >> 6][tid & 63] = qh[(size_t)(qbase + (tid >> 6)) * DH_ + (tid & 63)];
#pragma unroll
    for (int it = 0; it < 4; ++it) {
        const int i8 = (tid + it * 256) * 8;
        const int r = i8 >> 6, c = i8 & 63;
        uint4 v = *reinterpret_cast<const uint4*>(k2hb + i8);
        *reinterpret_cast<uint4*>(&k2s[r * K2S + c]) = v;
    }

    // k1 f32 fragments, kept across the q-loop. A[m=lane&15][k=quad*8+j]
    float k1f[2][2][8];
#pragma unroll
    for (int mt = 0; mt < 2; ++mt) {
        const int srow = (wv * 2 + mt) * 16 + row16;
#pragma unroll
        for (int kk = 0; kk < 2; ++kk) {
            const int k = kk * 32 + quad * 8;
            const float4 u0 = *reinterpret_cast<const float4*>(k1h + (size_t)srow * DH_ + k);
            const float4 u1 = *reinterpret_cast<const float4*>(k1h + (size_t)srow * DH_ + k + 4);
            k1f[mt][kk][0] = u0.x; k1f[mt][kk][1] = u0.y; k1f[mt][kk][2] = u0.z; k1f[mt][kk][3] = u0.w;
            k1f[mt][kk][4] = u1.x; k1f[mt][kk][5] = u1.y; k1f[mt][kk][6] = u1.z; k1f[mt][kk][7] = u1.w;
        }
    }
    __syncthreads();

    for (int qq = 0; qq < QB; ++qq) {
        const int qidx = qbase + qq;

        bf16x8 afrag[2][2];
#pragma unroll
        for (int mt = 0; mt < 2; ++mt)
#pragma unroll
            for (int kk = 0; kk < 2; ++kk) {
                const int k = kk * 32 + quad * 8;
                bf16x8 f;
#pragma unroll
                for (int j = 0; j < 8; ++j)
                    f[j] = (short)f2bf(k1f[mt][kk][j] * qv[qq][k + j]);
                afrag[mt][kk] = f;
            }

        f32x4 acc[2][8];
#pragma unroll
        for (int mt = 0; mt < 2; ++mt)
#pragma unroll
            for (int nt = 0; nt < 8; ++nt) acc[mt][nt] = (f32x4){0.f, 0.f, 0.f, 0.f};
#pragma unroll
        for (int kk = 0; kk < 2; ++kk)
#pragma unroll
            for (int nt = 0; nt < 8; ++nt) {
                bf16x8 bfrag = *reinterpret_cast<const bf16x8*>(
                    &k2s[(nt * 16 + row16) * K2S + kk * 32 + quad * 8]);
                acc[0][nt] = __builtin_amdgcn_mfma_f32_16x16x32_bf16(afrag[0][kk], bfrag, acc[0][nt], 0, 0, 0);
                acc[1][nt] = __builtin_amdgcn_mfma_f32_16x16x32_bf16(afrag[1][kk], bfrag, acc[1][nt], 0, 0, 0);
            }

        float rs[2][4], cs[8];
#pragma unroll
        for (int nt = 0; nt < 8; ++nt) cs[nt] = 0.f;
#pragma unroll
        for (int mt = 0; mt < 2; ++mt)
#pragma unroll
            for (int r = 0; r < 4; ++r) rs[mt][r] = 0.f;
#pragma unroll
        for (int nt = 0; nt < 8; ++nt) {
            const int t = nt * 16 + row16;
            const bool msk = (t > qidx);
#pragma unroll
            for (int mt = 0; mt < 2; ++mt)
#pragma unroll
                for (int r = 0; r < 4; ++r) {
                    float v = msk ? IGNORE_VAL : acc[mt][nt][r];
                    float p = __expf(v * (1.f / 64.f));
                    rs[mt][r] += p;
                    cs[nt] += p;
                }
        }

        // row sums across lane bits 0..3
#pragma unroll
        for (int m = 1; m < 16; m <<= 1)
#pragma unroll
            for (int mt = 0; mt < 2; ++mt)
#pragma unroll
                for (int r = 0; r < 4; ++r) rs[mt][r] += __shfl_xor(rs[mt][r], m, 64);
        if (row16 == 0) {
#pragma unroll
            for (int mt = 0; mt < 2; ++mt)
#pragma unroll
                for (int r = 0; r < 4; ++r)
                    Asm[qq][(wv * 2 + mt) * 16 + quad * 4 + r] = rs[mt][r];
        }

        // col sums across lane bits 4..5 -> per-wave partials
#pragma unroll
        for (int m = 16; m < 64; m <<= 1)
#pragma unroll
            for (int nt = 0; nt < 8; ++nt) cs[nt] += __shfl_xor(cs[nt], m, 64);
        if (quad == 0) {
#pragma unroll
            for (int nt = 0; nt < 8; ++nt) Atp[qq][wv][nt * 16 + row16] = cs[nt];
        }

        float tot = rs[0][0] + rs[0][1] + rs[0][2] + rs[0][3]
                  + rs[1][0] + rs[1][1] + rs[1][2] + rs[1][3];
#pragma unroll
        for (int m = 16; m < 64; m <<= 1) tot += __shfl_xor(tot, m, 64);
        if (lane == 0) reds[qq][wv] = tot;
    }
    __syncthreads();

    for (int i = tid; i < QB * S_; i += 256) {
        const int qq = i >> 7, t = i & 127;
        Atm[qq][t] = Atp[qq][0][t] + Atp[qq][1][t] + Atp[qq][2][t] + Atp[qq][3][t];
    }
    __syncthreads();

    // epilogue, s-major: read va/vb rows once, FMA into 4 q-accumulators
    {
        const int h = tid & 63, w = tid >> 6;
        float za[QB] = {0.f, 0.f, 0.f, 0.f};
        for (int i = 0; i < 32; ++i) {
            const int s = w * 32 + i;
            const float va_v = va_h[(size_t)s * DH_ + h];
            const float vb_v = vb_h[(size_t)s * DH_ + h];
#pragma unroll
            for (int qq = 0; qq < QB; ++qq)
                za[qq] += Asm[qq][s] * va_v + Atm[qq][s] * vb_v;
        }
#pragma unroll
        for (int qq = 0; qq < QB; ++qq) zred[w][qq][h] = za[qq];
    }
    __syncthreads();

    {
        const int qq = tid >> 6, h = tid & 63;
        const float Zv = reds[qq][0] + reds[qq][1] + reds[qq][2] + reds[qq][3];
        float zv = zred[0][qq][h] + zred[1][qq][h] + zred[2][qq][h] + zred[3][qq][h];
        zv = zv / Zv + b_v[n * DH_ + h];
        z_bf[((size_t)(b * S_ + qbase + qq) * (H_ * DH_)) + n * DH_ + h] = f2bf(zv);
    }
}

// ---------------- Kernel 3: out = z @ W_out + b_out (bf16 MFMA) -------------
// A = z_bf (256 x 512 bf16), W_out (512 x 512 f32). Tile 16 x 64, BK=64,
// grid (8, 16) = 128 blocks, 4 waves (wave w: cols w*16..w*16+15).
__global__ __launch_bounds__(256) void out_kernel(
    const unsigned short* __restrict__ z_bf,
    const float* __restrict__ W_out, const float* __restrict__ b_out,
    float* __restrict__ out)
{
    __shared__ __align__(16) unsigned short zs[16 * XT_ST];   // 2304 B
    __shared__ __align__(16) unsigned short Wt[64 * WT_ST];   // 8448 B

    const int cb = blockIdx.x;           // 0..7 (64 cols)
    const int rb = blockIdx.y;           // 0..15 (16 rows)
    const int tid = threadIdx.x;
    const int lane = tid & 63, wvx = tid >> 6;
    const int n16 = lane & 15, quad = lane >> 4;

    f32x4 acc = (f32x4){0.f, 0.f, 0.f, 0.f};

    for (int k0 = 0; k0 < 512; k0 += 64) {
        {   // stage z tile: 16 rows x 64 k, raw bf16 copy (uint2 = 4 elems/thread)
            const int m = tid >> 4, k4 = (tid & 15) * 4;
            uint2 v = *reinterpret_cast<const uint2*>(
                z_bf + (size_t)(rb * 16 + m) * 512 + k0 + k4);
            *reinterpret_cast<uint2*>(&zs[m * XT_ST + k4]) = v;
        }
        {   // stage W_out tile k-major
#pragma unroll
            for (int p = 0; p < 4; ++p) {
                const int k = p * 16 + (tid >> 4);
                const int nb = (tid & 15) * 4;
                const float4 v = *reinterpret_cast<const float4*>(
                    W_out + (size_t)(k0 + k) * 512 + cb * 64 + nb);
                *reinterpret_cast<unsigned int*>(&Wt[k * WT_ST + nb]) =
                    f2bf(v.x) | ((unsigned)f2bf(v.y) << 16);
                *reinterpret_cast<unsigned int*>(&Wt[k * WT_ST + nb + 2]) =
                    f2bf(v.z) | ((unsigned)f2bf(v.w) << 16);
            }
        }
        __syncthreads();
#pragma unroll
        for (int kk = 0; kk < 2; ++kk) {
            bf16x8 bf;
#pragma unroll
            for (int j = 0; j < 8; ++j)
                bf[j] = (short)Wt[(kk * 32 + quad * 8 + j) * WT_ST + wvx * 16 + n16];
            const bf16x8 af = *reinterpret_cast<const bf16x8*>(
                &zs[n16 * XT_ST + kk * 32 + quad * 8]);
            acc = __builtin_amdgcn_mfma_f32_16x16x32_bf16(af, bf, acc, 0, 0, 0);
        }
        __syncthreads();
    }

    const int c = cb * 64 + wvx * 16 + n16;
    const float bias = b_out[c];
#pragma unroll
    for (int r = 0; r < 4; ++r) {
        const int row = rb * 16 + quad * 4 + r;
        out[(size_t)row * 512 + c] = acc[r] + bias;
    }
}

// ---------------------------------------------------------------------------
extern "C" void kernel_launch(void* const* d_in, const int* in_sizes, int n_in,
                              void* d_out, int out_size, void* d_ws, size_t ws_size,
                              hipStream_t stream) {
    const float* x     = (const float*)d_in[0];
    const float* W_kkq = (const float*)d_in[1];
    const float* b_kkq = (const float*)d_in[2];
    const float* Wv_a  = (const float*)d_in[3];
    const float* Wv_b  = (const float*)d_in[4];
    const float* b_v   = (const float*)d_in[5];
    const float* W_out = (const float*)d_in[6];
    const float* b_out = (const float*)d_in[7];
    float* out = (float*)d_out;

    const size_t HE = (size_t)B_ * H_ * S_ * DH_;   // 131072
    float* ws = (float*)d_ws;
    float* k1_ws = ws;
    float* q_ws  = ws + HE;
    float* va_ws = ws + 2 * HE;
    float* vb_ws = ws + 3 * HE;
    unsigned short* k2bf = (unsigned short*)(ws + 4 * HE);          // HE ushorts
    unsigned short* z_bf = (unsigned short*)(ws + 4 * HE) + HE;     // HE ushorts

    proj_kernel<<<dim3(40, 8), 256, 0, stream>>>(x, W_kkq, b_kkq, Wv_a, Wv_b,
                                                 k1_ws, k2bf, q_ws, va_ws, vb_ws);
    tri_kernel<<<dim3(S_ / QB, H_, B_), 256, 0, stream>>>(k1_ws, k2bf, q_ws,
                                                          va_ws, vb_ws, b_v, z_bf);
    out_kernel<<<dim3(8, 16), 256, 0, stream>>>(z_bf, W_out, b_out, out);
}